// Round 1
// baseline (1230.458 us; speedup 1.0000x reference)
//
#include <hip/hip_runtime.h>
#include <math.h>

// Problem constants (match reference)
#define LD   32
#define HID  64
#define NN   65536
#define BB   32
#define CHUNK 255                 // outputs per block (256 interfaces)
constexpr float FLUX_SCALE = 0.25f;
constexpr float RDTDX      = 0.5f;   // DT/DX = 0.0005/0.001

__device__ __forceinline__ float gelu_exact(float x) {
    return 0.5f * x * (1.0f + erff(x * 0.70710678118654752f));
}

__global__ __launch_bounds__(256, 2)
void fluxgnn_kernel(const float* __restrict__ u,
                    const float* __restrict__ enc,
                    const float* __restrict__ W1,
                    const float* __restrict__ b1,
                    const float* __restrict__ W2,
                    const float* __restrict__ b2,
                    const float* __restrict__ W3,
                    const float* __restrict__ b3,
                    float* __restrict__ out)
{
    __shared__ float sv1[HID];
    __shared__ float sv2[HID];
    __shared__ float sphi[256];

    const int t = threadIdx.x;
    const int chunks_per_row = (NN + CHUNK - 1) / CHUNK;   // 258
    const int row   = blockIdx.x / chunks_per_row;
    const int chunk = blockIdx.x % chunks_per_row;
    const long n0   = (long)chunk * CHUNK;

    // ---- per-block precompute: v1[j] = enc . W1[0:32, j], v2[j] = |enc| . W1[32:64, j]
    if (t < HID) {
        float a1 = 0.f, a2 = 0.f;
        #pragma unroll
        for (int k = 0; k < LD; ++k) {
            const float e = enc[k];
            a1 = fmaf(e,        W1[k * HID + t],        a1);
            a2 = fmaf(fabsf(e), W1[(LD + k) * HID + t], a2);
        }
        sv1[t] = a1;
        sv2[t] = a2;
    }

    // S = sum(enc^2) — uniform, cheap, every thread computes it
    float S = 0.f;
    #pragma unroll
    for (int k = 0; k < LD; ++k) { const float e = enc[k]; S = fmaf(e, e, S); }
    const float inv  = 1.0f / (S + 1e-12f);
    const float selt = S * inv;          // scale on the u-passthrough term

    __syncthreads();

    // ---- each thread computes phi at interface i = n0 + t  (i in [0, NN])
    const long i = n0 + t;
    const float* __restrict__ urow = u + (long)row * NN;
    float phi = 0.f;
    if (i <= NN) {
        const float ul = urow[(i == 0)  ? 0        : (i - 1)];
        const float ur = urow[(i >= NN) ? (NN - 1) : i];
        const float a = ul + ur;
        const float d = fabsf(ur - ul);

        // layer 1: x1 = gelu(a*v1 + d*v2 + b1)
        float x1[HID];
        #pragma unroll
        for (int k = 0; k < HID; ++k) {
            x1[k] = gelu_exact(fmaf(a, sv1[k], fmaf(d, sv2[k], b1[k])));
        }

        // layers 2+3 fused: f3 accumulates W3 contributions as each x2[j] is made
        float f3[LD];
        #pragma unroll
        for (int m = 0; m < LD; ++m) f3[m] = b3[m];

        #pragma unroll 4
        for (int j = 0; j < HID; ++j) {
            float acc = b2[j];
            #pragma unroll
            for (int k = 0; k < HID; ++k)
                acc = fmaf(x1[k], W2[k * HID + j], acc);
            const float xj = gelu_exact(acc);
            #pragma unroll
            for (int m = 0; m < LD; ++m)
                f3[m] = fmaf(xj, W3[j * LD + m], f3[m]);
        }

        float q = 0.f;
        #pragma unroll
        for (int m = 0; m < LD; ++m)
            q = fmaf(tanhf(f3[m]), enc[m], q);
        phi = q * FLUX_SCALE * inv;
    }
    sphi[t] = phi;
    __syncthreads();

    // ---- outputs n = n0 + t for t < CHUNK
    if (t < CHUNK) {
        const long n = n0 + t;
        if (n < NN) {
            const float un = urow[n];
            out[(long)row * NN + n] = fmaf(un, selt, -RDTDX * (sphi[t + 1] - sphi[t]));
        }
    }
}

extern "C" void kernel_launch(void* const* d_in, const int* in_sizes, int n_in,
                              void* d_out, int out_size, void* d_ws, size_t ws_size,
                              hipStream_t stream) {
    const float* u   = (const float*)d_in[0];
    const float* enc = (const float*)d_in[1];
    const float* W1  = (const float*)d_in[2];
    const float* b1  = (const float*)d_in[3];
    const float* W2  = (const float*)d_in[4];
    const float* b2  = (const float*)d_in[5];
    const float* W3  = (const float*)d_in[6];
    const float* b3  = (const float*)d_in[7];
    float* out = (float*)d_out;

    const int chunks_per_row = (NN + CHUNK - 1) / CHUNK;   // 258
    const int grid = BB * chunks_per_row;                  // 8256 blocks
    fluxgnn_kernel<<<grid, 256, 0, stream>>>(u, enc, W1, b1, W2, b2, W3, b3, out);
}

// Round 2
// 179.047 us; speedup vs baseline: 6.8723x; 6.8723x over previous
//
#include <hip/hip_runtime.h>
#include <math.h>
#include <stdint.h>

// FluxGNN1DLatent — MFMA formulation.
// Algebra: out[b,n] = u[b,n]*S/(S+eps) - 0.5*(phi[n+1]-phi[n]),
//   phi[i] = 0.25/(S+eps) * sum_m enc[m]*tanh(f3[i][m]),
//   f3 = x2@W3+b3, x2 = gelu(x1@W2+b2), x1[i][k] = gelu(a_i*v1[k]+d_i*v2[k]+b1[k]),
//   v1 = enc^T W1[:32], v2 = |enc|^T W1[32:], a=ul+ur, d=|ur-ul|, S=sum(enc^2).
// One wave handles 64 interfaces (63 outputs). Both matmuls run as swapped
// MFMA (C' = W^T · X^T) on 16x16x32 bf16 tiles, so weights are A-fragments
// loaded once per wave, and layer-1 is generated directly in B-frag layout.

#define LD    32
#define HID   64
#define NN    65536
#define BB    32
#define SPANS 1041          // ceil(65536/63); 1041*63 = 65583 >= 65536
#define WPB   4             // waves per block

typedef __attribute__((ext_vector_type(8))) short bf16x8;
typedef __attribute__((ext_vector_type(4))) float f32x4;

__device__ __forceinline__ short f2bf(float f) {
    uint32_t x = __float_as_uint(f);
    return (short)((x + 0x7FFFu + ((x >> 16) & 1u)) >> 16);   // RNE
}
__device__ __forceinline__ uint32_t pack_bf2(float lo, float hi) {
    return (uint32_t)(uint16_t)f2bf(lo) | ((uint32_t)(uint16_t)f2bf(hi) << 16);
}
__device__ __forceinline__ float tanh_fast(float y) {
    // tanh(y) = 1 - 2/(e^{2y}+1); branchless, saturates correctly at +-inf
    float t = __expf(2.0f * y);
    return 1.0f - 2.0f * __builtin_amdgcn_rcpf(t + 1.0f);
}
__device__ __forceinline__ float gelu_fast(float x) {
    float arg = 0.7978845608028654f * x * fmaf(0.044715f, x * x, 1.0f);
    return 0.5f * x * (1.0f + tanh_fast(arg));
}

__global__ __launch_bounds__(256, 2)
void fluxgnn_mfma(const float* __restrict__ u,  const float* __restrict__ enc,
                  const float* __restrict__ W1, const float* __restrict__ b1,
                  const float* __restrict__ W2, const float* __restrict__ b2,
                  const float* __restrict__ W3, const float* __restrict__ b3,
                  float* __restrict__ out)
{
    __shared__ __align__(16) short xT[WPB][64][64];   // per-wave x2^T tile (8KB each)
    __shared__ float sv1[HID], sv2[HID];
    __shared__ float sphi[WPB][64];

    const int tid = threadIdx.x;
    const int w   = tid >> 6;        // wave in block
    const int l   = tid & 63;        // lane
    const int c   = l & 15;          // frag column / row-low
    const int g   = l >> 4;          // frag k-group

    // ---- block-cooperative: v1[j] = enc.W1[0:32,j], v2[j] = |enc|.W1[32:64,j]
    if (tid < HID) {
        float a1 = 0.f, a2 = 0.f;
        #pragma unroll
        for (int m = 0; m < LD; ++m) {
            const float e = enc[m];
            a1 = fmaf(e,        W1[m * HID + tid],        a1);
            a2 = fmaf(fabsf(e), W1[(LD + m) * HID + tid], a2);
        }
        sv1[tid] = a1;
        sv2[tid] = a2;
    }

    float S = 0.f;
    #pragma unroll
    for (int m = 0; m < LD; ++m) { const float e = enc[m]; S = fmaf(e, e, S); }
    const float inv  = 1.0f / (S + 1e-12f);
    const float selt = S * inv;

    const int wave_id = blockIdx.x * WPB + w;
    const int row  = wave_id / SPANS;
    const int span = wave_id % SPANS;
    const int n0   = span * 63;
    const float* __restrict__ urow = u + row * NN;

    // ---- per-wave constant fragments (loaded once)
    // A2 = W2^T : M=h2(64) x K=h1(64) -> mt 0..3, kt 0..1
    bf16x8 a2f[4][2];
    #pragma unroll
    for (int mt = 0; mt < 4; ++mt)
        #pragma unroll
        for (int kt = 0; kt < 2; ++kt)
            #pragma unroll
            for (int j = 0; j < 8; ++j)
                a2f[mt][kt][j] = f2bf(W2[(32*kt + 8*g + j) * HID + 16*mt + c]);

    // A3 = W3^T : M=ld(32) x K=h2(64) -> mt 0..1, kt 0..1
    bf16x8 a3f[2][2];
    #pragma unroll
    for (int mt = 0; mt < 2; ++mt)
        #pragma unroll
        for (int kt = 0; kt < 2; ++kt)
            #pragma unroll
            for (int j = 0; j < 8; ++j)
                a3f[mt][kt][j] = f2bf(W3[(32*kt + 8*g + j) * LD + 16*mt + c]);

    float b2g[16];
    #pragma unroll
    for (int mt = 0; mt < 4; ++mt)
        #pragma unroll
        for (int q = 0; q < 4; ++q) b2g[mt*4+q] = b2[16*mt + 4*g + q];

    float b3g[8], encg[8];
    #pragma unroll
    for (int mt = 0; mt < 2; ++mt)
        #pragma unroll
        for (int q = 0; q < 4; ++q) {
            b3g[mt*4+q]  = b3[16*mt + 4*g + q];
            encg[mt*4+q] = enc[16*mt + 4*g + q];
        }

    __syncthreads();

    // per-lane layer-1 coefficients at its 16 k-values (k = 32*kt + 8*g + j)
    float v1g[16], v2g[16], b1g[16];
    #pragma unroll
    for (int kt = 0; kt < 2; ++kt)
        #pragma unroll
        for (int j = 0; j < 8; ++j) {
            const int k1 = 32*kt + 8*g + j;
            v1g[kt*8+j] = sv1[k1];
            v2g[kt*8+j] = sv2[k1];
            b1g[kt*8+j] = b1[k1];
        }

    // ---- u features for this lane's 4 interfaces (i = n0 + 16*nt + c)
    float af[4], df[4];
    #pragma unroll
    for (int nt = 0; nt < 4; ++nt) {
        const int i  = n0 + 16*nt + c;
        int il = i - 1; il = il < 0 ? 0 : (il > NN-1 ? NN-1 : il);
        const int ir = i > NN-1 ? NN-1 : i;
        const float ul = urow[il], ur = urow[ir];
        af[nt] = ul + ur;
        df[nt] = fabsf(ur - ul);
    }

    short* const xbase = &xT[w][0][0];

    // ---- layer 2 (swapped): C2[h2][i] per nt-column-block
    #pragma unroll
    for (int nt = 0; nt < 4; ++nt) {
        f32x4 acc[4];
        #pragma unroll
        for (int mt = 0; mt < 4; ++mt) acc[mt] = (f32x4){0.f, 0.f, 0.f, 0.f};

        #pragma unroll
        for (int kt = 0; kt < 2; ++kt) {
            bf16x8 bfrag;   // B2 = x1^T frag: k = 32kt+8g+j, n-col = c
            #pragma unroll
            for (int j = 0; j < 8; ++j) {
                const float pre = fmaf(af[nt], v1g[kt*8+j],
                                  fmaf(df[nt], v2g[kt*8+j], b1g[kt*8+j]));
                bfrag[j] = f2bf(gelu_fast(pre));
            }
            #pragma unroll
            for (int mt = 0; mt < 4; ++mt)
                acc[mt] = __builtin_amdgcn_mfma_f32_16x16x32_bf16(
                              a2f[mt][kt], bfrag, acc[mt], 0, 0, 0);
        }

        // gelu(+b2) and transpose-store x2^T -> xT[i][h2], XOR-swizzled 8B chunks
        const int rowl = 16*nt + c;
        #pragma unroll
        for (int mt = 0; mt < 4; ++mt) {
            const float y0 = gelu_fast(acc[mt][0] + b2g[mt*4+0]);
            const float y1 = gelu_fast(acc[mt][1] + b2g[mt*4+1]);
            const float y2 = gelu_fast(acc[mt][2] + b2g[mt*4+2]);
            const float y3 = gelu_fast(acc[mt][3] + b2g[mt*4+3]);
            const int cs = (4*mt + g) ^ ((c & 7) << 1);   // 8B-chunk swizzle
            uint2 pk;
            pk.x = pack_bf2(y0, y1);
            pk.y = pack_bf2(y2, y3);
            *reinterpret_cast<uint2*>(xbase + rowl*64 + cs*4) = pk;
        }
    }

    // ---- layer 3 (swapped): C3[ld][i]; B3 frags read back via swizzled b128
    f32x4 acc3[2][4];
    #pragma unroll
    for (int mt = 0; mt < 2; ++mt)
        #pragma unroll
        for (int nt = 0; nt < 4; ++nt) acc3[mt][nt] = (f32x4){0.f, 0.f, 0.f, 0.f};

    #pragma unroll
    for (int kt = 0; kt < 2; ++kt)
        #pragma unroll
        for (int nt = 0; nt < 4; ++nt) {
            const int rowl = 16*nt + c;
            const int p = (8*kt + 2*g) ^ ((c & 7) << 1);  // even -> 16B aligned
            const bf16x8 bfr = *reinterpret_cast<const bf16x8*>(xbase + rowl*64 + p*4);
            #pragma unroll
            for (int mt = 0; mt < 2; ++mt)
                acc3[mt][nt] = __builtin_amdgcn_mfma_f32_16x16x32_bf16(
                                   a3f[mt][kt], bfr, acc3[mt][nt], 0, 0, 0);
        }

    // ---- tanh + dec-dot + 4-lane (g) reduction -> phi per interface
    float phi_[4];
    #pragma unroll
    for (int nt = 0; nt < 4; ++nt) {
        float s = 0.f;
        #pragma unroll
        for (int mt = 0; mt < 2; ++mt)
            #pragma unroll
            for (int q = 0; q < 4; ++q) {
                const float f = acc3[mt][nt][q] + b3g[mt*4+q];
                s = fmaf(tanh_fast(f), encg[mt*4+q], s);
            }
        s += __shfl_xor(s, 16);
        s += __shfl_xor(s, 32);
        phi_[nt] = s * (0.25f * inv);
    }
    float myphi = phi_[0];
    if (g == 1) myphi = phi_[1];
    if (g == 2) myphi = phi_[2];
    if (g == 3) myphi = phi_[3];
    sphi[w][16*g + c] = myphi;     // lane (g,c) publishes interface 16g+c

    // ---- outputs n = n0 + l, l < 63 (wave-local LDS, no barrier needed)
    if (l < 63) {
        const int n = n0 + l;
        if (n < NN) {
            const float pn  = sphi[w][l];
            const float pn1 = sphi[w][l + 1];
            out[row * NN + n] = fmaf(urow[n], selt, -0.5f * (pn1 - pn));
        }
    }
}

extern "C" void kernel_launch(void* const* d_in, const int* in_sizes, int n_in,
                              void* d_out, int out_size, void* d_ws, size_t ws_size,
                              hipStream_t stream) {
    const float* u   = (const float*)d_in[0];
    const float* enc = (const float*)d_in[1];
    const float* W1  = (const float*)d_in[2];
    const float* b1  = (const float*)d_in[3];
    const float* W2  = (const float*)d_in[4];
    const float* b2  = (const float*)d_in[5];
    const float* W3  = (const float*)d_in[6];
    const float* b3  = (const float*)d_in[7];
    float* out = (float*)d_out;

    const int total_waves = BB * SPANS;          // 33312
    const int grid = total_waves / WPB;          // 8328 (exact)
    fluxgnn_mfma<<<grid, 64 * WPB, 0, stream>>>(u, enc, W1, b1, W2, b2, W3, b3, out);
}

// Round 3
// 123.996 us; speedup vs baseline: 9.9233x; 1.4440x over previous
//
#include <hip/hip_runtime.h>
#include <math.h>
#include <stdint.h>

// FluxGNN1DLatent — MFMA formulation, round 3.
// out[b,n] = u[b,n]*S/(S+eps) - 0.5*(phi[n+1]-phi[n]),
//   phi[i] = 0.25/(S+eps) * sum_m enc[m]*tanh(f3[i][m]),
//   f3 = x2@W3+b3, x2 = gelu(x1@W2+b2), x1[i][k] = gelu(a_i*v1[k]+d_i*v2[k]+b1[k]),
//   v1 = enc^T W1[:32], v2 = |enc|^T W1[32:], a=ul+ur, d=|ur-ul|, S=sum(enc^2).
// One wave = 64 interfaces (63 outputs); persistent waves loop over spans so
// the per-wave weight-fragment prologue amortizes. Activations use
// exp2-folded tanh-form gelu (5 VALU + 2 trans), float2 packed math
// (v_pk_fma_f32), and v_cvt_pk_bf16_f32 for bf16 packing.

#define LD    32
#define HID   64
#define NN    65536
#define BB    32
#define SPANS 1041                 // ceil(65536/63)
#define WPB   4
#define GRID  2048
#define TOTAL_SPANS (BB * SPANS)   // 33312

typedef __attribute__((ext_vector_type(8))) short bf16x8;
typedef __attribute__((ext_vector_type(4))) float f32x4;
typedef __attribute__((ext_vector_type(2))) float v2f;
typedef __attribute__((ext_vector_type(4))) unsigned int u32x4;

__device__ __forceinline__ uint32_t cvt_pk_bf16(float lo, float hi) {
    uint32_t r;
    asm("v_cvt_pk_bf16_f32 %0, %1, %2" : "=v"(r) : "v"(lo), "v"(hi));
    return r;
}

// gelu(x) = x*(1 - 1/(exp2(C1*x + C3*x^3) + 1));  C1=2*log2e*0.7978845608,
// C3=C1*0.044715 — identical math to tanh-form gelu, exp2-folded.
__device__ __forceinline__ v2f gelu2(v2f x) {
    const v2f xx    = x * x;
    const v2f inner = xx * 0.10294322f + 2.3022077f;
    const v2f arg   = x * inner;
    v2f t;
    t.x = __builtin_amdgcn_exp2f(arg.x);
    t.y = __builtin_amdgcn_exp2f(arg.y);
    const v2f d = t + 1.0f;
    v2f r;
    r.x = __builtin_amdgcn_rcpf(d.x);
    r.y = __builtin_amdgcn_rcpf(d.y);
    return x - x * r;
}

// tanh(y) = 1 - 2/(exp2(C2*y)+1); C2 = 2*log2e
__device__ __forceinline__ v2f tanh2(v2f y) {
    const v2f a = y * 2.8853901f;
    v2f t;
    t.x = __builtin_amdgcn_exp2f(a.x);
    t.y = __builtin_amdgcn_exp2f(a.y);
    const v2f d = t + 1.0f;
    v2f r;
    r.x = __builtin_amdgcn_rcpf(d.x);
    r.y = __builtin_amdgcn_rcpf(d.y);
    return 1.0f - 2.0f * r;
}

__global__ __launch_bounds__(256, 2)
void fluxgnn_mfma(const float* __restrict__ u,  const float* __restrict__ enc,
                  const float* __restrict__ W1, const float* __restrict__ b1,
                  const float* __restrict__ W2, const float* __restrict__ b2,
                  const float* __restrict__ W3, const float* __restrict__ b3,
                  float* __restrict__ out)
{
    __shared__ __align__(16) short xT[WPB][64][64];   // per-wave x2^T tile
    __shared__ __align__(16) float sv1[HID];
    __shared__ __align__(16) float sv2[HID];
    __shared__ float sphi[WPB][64];

    const int tid = threadIdx.x;
    const int w   = tid >> 6;
    const int l   = tid & 63;
    const int c   = l & 15;
    const int g   = l >> 4;

    // ---- block-cooperative: v1[j] = enc.W1[0:32,j], v2[j] = |enc|.W1[32:64,j]
    if (tid < HID) {
        float a1 = 0.f, a2 = 0.f;
        #pragma unroll
        for (int m = 0; m < LD; ++m) {
            const float e = enc[m];
            a1 = fmaf(e,        W1[m * HID + tid],        a1);
            a2 = fmaf(fabsf(e), W1[(LD + m) * HID + tid], a2);
        }
        sv1[tid] = a1;
        sv2[tid] = a2;
    }

    float S = 0.f;
    #pragma unroll
    for (int m = 0; m < LD; ++m) { const float e = enc[m]; S = fmaf(e, e, S); }
    const float inv  = 1.0f / (S + 1e-12f);
    const float selt = S * inv;

    // ---- per-wave constant fragments (once, amortized over spans)
    // A2 = W2^T : lane (g,c) holds A[m=16mt+c][k=32kt+8g+j]
    bf16x8 a2f[4][2];
    #pragma unroll
    for (int mt = 0; mt < 4; ++mt)
        #pragma unroll
        for (int kt = 0; kt < 2; ++kt) {
            u32x4 uu;
            #pragma unroll
            for (int p = 0; p < 4; ++p) {
                const int k0 = 32*kt + 8*g + 2*p;
                uu[p] = cvt_pk_bf16(W2[k0 * HID + 16*mt + c],
                                    W2[(k0 + 1) * HID + 16*mt + c]);
            }
            a2f[mt][kt] = __builtin_bit_cast(bf16x8, uu);
        }

    bf16x8 a3f[2][2];
    #pragma unroll
    for (int mt = 0; mt < 2; ++mt)
        #pragma unroll
        for (int kt = 0; kt < 2; ++kt) {
            u32x4 uu;
            #pragma unroll
            for (int p = 0; p < 4; ++p) {
                const int k0 = 32*kt + 8*g + 2*p;
                uu[p] = cvt_pk_bf16(W3[k0 * LD + 16*mt + c],
                                    W3[(k0 + 1) * LD + 16*mt + c]);
            }
            a3f[mt][kt] = __builtin_bit_cast(bf16x8, uu);
        }

    const v2f* b2v  = (const v2f*)b2;
    const v2f* b3v  = (const v2f*)b3;
    const v2f* encv = (const v2f*)enc;
    v2f b2p[4][2];
    #pragma unroll
    for (int mt = 0; mt < 4; ++mt) {
        b2p[mt][0] = b2v[8*mt + 2*g + 0];
        b2p[mt][1] = b2v[8*mt + 2*g + 1];
    }
    v2f b3p[2][2], encp[2][2];
    #pragma unroll
    for (int mt = 0; mt < 2; ++mt) {
        b3p[mt][0]  = b3v[8*mt + 2*g + 0];
        b3p[mt][1]  = b3v[8*mt + 2*g + 1];
        encp[mt][0] = encv[8*mt + 2*g + 0];
        encp[mt][1] = encv[8*mt + 2*g + 1];
    }

    __syncthreads();

    // per-lane layer-1 coefficient pairs at k = 32kt + 8g + 2p (+1)
    const v2f* sv1v = (const v2f*)sv1;
    const v2f* sv2v = (const v2f*)sv2;
    const v2f* b1v  = (const v2f*)b1;
    v2f v1p[2][4], v2p[2][4], b1p[2][4];
    #pragma unroll
    for (int kt = 0; kt < 2; ++kt)
        #pragma unroll
        for (int p = 0; p < 4; ++p) {
            const int idx = 16*kt + 4*g + p;
            v1p[kt][p] = sv1v[idx];
            v2p[kt][p] = sv2v[idx];
            b1p[kt][p] = b1v[idx];
        }

    short* const xbase = &xT[w][0][0];
    const int swz = (c & 7) << 1;

    // ---- persistent span loop
    for (int sid = blockIdx.x * WPB + w; sid < TOTAL_SPANS; sid += GRID * WPB) {
        const int row  = sid / SPANS;
        const int span = sid - row * SPANS;
        const int n0   = span * 63;
        const float* __restrict__ urow = u + row * NN;

        // u features for this lane's 4 interfaces (i = n0 + 16*nt + c)
        float af[4], df[4];
        #pragma unroll
        for (int nt = 0; nt < 4; ++nt) {
            const int i = n0 + 16*nt + c;
            int il = i - 1; il = il < 0 ? 0 : (il > NN-1 ? NN-1 : il);
            const int ir = i > NN-1 ? NN-1 : i;
            const float ul = urow[il], ur = urow[ir];
            af[nt] = ul + ur;
            df[nt] = fabsf(ur - ul);
        }

        // ---- layer 1+2 (swapped): C2[h2][i] per nt-column-block
        #pragma unroll
        for (int nt = 0; nt < 4; ++nt) {
            const v2f av = { af[nt], af[nt] };
            const v2f dv = { df[nt], df[nt] };
            f32x4 acc[4];
            #pragma unroll
            for (int mt = 0; mt < 4; ++mt) acc[mt] = (f32x4){0.f, 0.f, 0.f, 0.f};

            #pragma unroll
            for (int kt = 0; kt < 2; ++kt) {
                u32x4 uu;
                #pragma unroll
                for (int p = 0; p < 4; ++p) {
                    const v2f pre = av * v1p[kt][p] + (dv * v2p[kt][p] + b1p[kt][p]);
                    const v2f gg  = gelu2(pre);
                    uu[p] = cvt_pk_bf16(gg.x, gg.y);
                }
                const bf16x8 bfrag = __builtin_bit_cast(bf16x8, uu);
                #pragma unroll
                for (int mt = 0; mt < 4; ++mt)
                    acc[mt] = __builtin_amdgcn_mfma_f32_16x16x32_bf16(
                                  a2f[mt][kt], bfrag, acc[mt], 0, 0, 0);
            }

            // gelu(+b2), pack, transpose-store x2^T (XOR-swizzled 8B chunks)
            const int rowoff = (16*nt + c) * 64;
            #pragma unroll
            for (int mt = 0; mt < 4; ++mt) {
                const v2f y01 = gelu2((v2f){acc[mt][0], acc[mt][1]} + b2p[mt][0]);
                const v2f y23 = gelu2((v2f){acc[mt][2], acc[mt][3]} + b2p[mt][1]);
                uint2 pk;
                pk.x = cvt_pk_bf16(y01.x, y01.y);
                pk.y = cvt_pk_bf16(y23.x, y23.y);
                const int cs = (4*mt + g) ^ swz;
                *reinterpret_cast<uint2*>(xbase + rowoff + cs*4) = pk;
            }
        }

        // ---- layer 3 (swapped): C3[ld][i]
        f32x4 acc3[2][4];
        #pragma unroll
        for (int mt = 0; mt < 2; ++mt)
            #pragma unroll
            for (int nt = 0; nt < 4; ++nt) acc3[mt][nt] = (f32x4){0.f, 0.f, 0.f, 0.f};

        #pragma unroll
        for (int kt = 0; kt < 2; ++kt)
            #pragma unroll
            for (int nt = 0; nt < 4; ++nt) {
                const int p = (8*kt + 2*g) ^ swz;   // even -> 16B aligned
                const bf16x8 bfr =
                    *reinterpret_cast<const bf16x8*>(xbase + (16*nt + c)*64 + p*4);
                #pragma unroll
                for (int mt = 0; mt < 2; ++mt)
                    acc3[mt][nt] = __builtin_amdgcn_mfma_f32_16x16x32_bf16(
                                       a3f[mt][kt], bfr, acc3[mt][nt], 0, 0, 0);
            }

        // ---- tanh + dec-dot + g-group reduction -> phi
        float phi_[4];
        #pragma unroll
        for (int nt = 0; nt < 4; ++nt) {
            v2f sacc = {0.f, 0.f};
            #pragma unroll
            for (int mt = 0; mt < 2; ++mt) {
                const v2f f01 = (v2f){acc3[mt][nt][0], acc3[mt][nt][1]} + b3p[mt][0];
                const v2f f23 = (v2f){acc3[mt][nt][2], acc3[mt][nt][3]} + b3p[mt][1];
                sacc += tanh2(f01) * encp[mt][0];
                sacc += tanh2(f23) * encp[mt][1];
            }
            float s = sacc.x + sacc.y;
            s += __shfl_xor(s, 16);
            s += __shfl_xor(s, 32);
            phi_[nt] = s * (0.25f * inv);
        }
        float myphi = phi_[0];
        if (g == 1) myphi = phi_[1];
        if (g == 2) myphi = phi_[2];
        if (g == 3) myphi = phi_[3];
        sphi[w][16*g + c] = myphi;

        // ---- outputs n = n0 + l, l < 63 (wave-local, no barrier)
        if (l < 63) {
            const int n = n0 + l;
            if (n < NN) {
                const float pn  = sphi[w][l];
                const float pn1 = sphi[w][l + 1];
                out[row * NN + n] = fmaf(urow[n], selt, -0.5f * (pn1 - pn));
            }
        }
    }
}

extern "C" void kernel_launch(void* const* d_in, const int* in_sizes, int n_in,
                              void* d_out, int out_size, void* d_ws, size_t ws_size,
                              hipStream_t stream) {
    const float* u   = (const float*)d_in[0];
    const float* enc = (const float*)d_in[1];
    const float* W1  = (const float*)d_in[2];
    const float* b1  = (const float*)d_in[3];
    const float* W2  = (const float*)d_in[4];
    const float* b2  = (const float*)d_in[5];
    const float* W3  = (const float*)d_in[6];
    const float* b3  = (const float*)d_in[7];
    float* out = (float*)d_out;

    fluxgnn_mfma<<<GRID, 64 * WPB, 0, stream>>>(u, enc, W1, b1, W2, b2, W3, b3, out);
}